// Round 5
// baseline (500.412 us; speedup 1.0000x reference)
//
#include <hip/hip_runtime.h>

#define NNODES 10000
#define NEDGES 160000
#define NB 8
#define NC 32
#define PADE 230016   // >= NEDGES + 7*NNODES (buckets padded to multiple of 8)
#define LUTB 2048
constexpr float NEG_SLOPE = 0.01f;

__device__ __forceinline__ float sigmoidf_(float x) {
    return 1.0f / (1.0f + __expf(-x));
}

// ---- setup: zero counters, sentinel-fill sorted arrays, build sige LUT, fold att weights ----
// consts: [0:32) aq1, [32:64) ak1, [64:96) aq2, [96:128) ak2, [128] ce1, [129] ce2
__global__ __launch_bounds__(256) void setup_kernel(
    const float* Q1, const float* K1, const float* aw1, const float* We1,
    const float* Q2, const float* K2, const float* aw2, const float* We2,
    float* consts, float* lut,
    int* srcs1, int* srcs2, float* ws1, float* ws2,
    int* cnt, int* nodectr,
    float* xs1, float* xs2,
    float* sq1, float* sk1, float* sq2, float* sk2)
{
    if (blockIdx.x == gridDim.x - 1) {
        int t = threadIdx.x;
        if (t < 32) {
            float aq1 = 0.f, ak1 = 0.f, aq2 = 0.f, ak2 = 0.f;
            for (int s = 0; s < 32; ++s) {
                aq1 += Q1[t * 32 + s] * aw1[s];
                ak1 += K1[t * 32 + s] * aw1[32 + s];
                aq2 += Q2[t * 32 + s] * aw2[s];
                ak2 += K2[t * 32 + s] * aw2[32 + s];
            }
            consts[t]      = aq1;
            consts[32 + t] = ak1;
            consts[64 + t] = aq2;
            consts[96 + t] = ak2;
            if (t == 0) {
                float ce1 = 0.f, ce2 = 0.f;
                for (int s = 0; s < 32; ++s) {
                    ce1 += We1[s] * aw1[64 + s];
                    ce2 += We2[s] * aw2[64 + s];
                }
                consts[128] = ce1;
                consts[129] = ce2;
            }
        }
        return;
    }
    int i = blockIdx.x * 256 + threadIdx.x;
    if (i < PADE) {
        srcs1[i] = NNODES; srcs2[i] = NNODES;
        ws1[i] = 0.f;      ws2[i] = 0.f;
    }
    if (i < 2 * LUTB * 32) {             // sige LUT, both layers
        int layer = i >> 16;             // LUTB*32 = 65536
        int bin   = (i >> 5) & (LUTB - 1);
        int o     = i & 31;
        float w   = (bin + 0.5f) * (1.0f / LUTB);
        float we  = layer ? We2[o] : We1[o];
        lut[i] = sigmoidf_(w * we);
    }
    if (i < 2 * NNODES) cnt[i] = 0;
    if (i < 2) nodectr[i * 16] = 0;
    if (i < NB * NC) {
        xs1[(size_t)NNODES * NB * NC + i] = 0.f;
        xs2[(size_t)NNODES * NB * NC + i] = 0.f;
    }
    if (i < NB) {
        sq1[NNODES * NB + i] = 0.f; sk1[NNODES * NB + i] = 0.f;
        sq2[NNODES * NB + i] = 0.f; sk2[NNODES * NB + i] = 0.f;
    }
}

__global__ __launch_bounds__(256) void hist_kernel(
    const int* __restrict__ ei0, const int* __restrict__ ei1, int* __restrict__ cnt01)
{
    int e = blockIdx.x * 256 + threadIdx.x;
    const int* ei = blockIdx.y ? ei1 : ei0;
    int* cnt = cnt01 + blockIdx.y * NNODES;
    if (e < NEDGES) atomicAdd(&cnt[ei[NEDGES + e]], 1);
}

// block per layer: exclusive scan of counts rounded up to multiple of 8
__global__ __launch_bounds__(1024) void scan_kernel(int* cnt01, int* rowptr01)
{
    __shared__ int part[1024];
    int layer = blockIdx.x;
    int* cnt    = cnt01 + layer * NNODES;
    int* rowptr = rowptr01 + layer * (NNODES + 1);
    int t = threadIdx.x;
    int base = t * 10;
    int local[10];
    int s = 0;
    #pragma unroll
    for (int i = 0; i < 10; ++i) {
        int idx = base + i;
        int v = (idx < NNODES) ? cnt[idx] : 0;
        int vp = (v + 7) & ~7;
        local[i] = s;
        s += vp;
    }
    part[t] = s;
    __syncthreads();
    for (int off = 1; off < 1024; off <<= 1) {
        int v = (t >= off) ? part[t - off] : 0;
        __syncthreads();
        part[t] += v;
        __syncthreads();
    }
    int pre = (t == 0) ? 0 : part[t - 1];
    #pragma unroll
    for (int i = 0; i < 10; ++i) {
        int idx = base + i;
        if (idx < NNODES) {
            int p = pre + local[i];
            rowptr[idx] = p;
            cnt[idx]    = p;            // becomes scatter cursor
        }
    }
    if (t == 1023) rowptr[NNODES] = part[1023];
}

__global__ __launch_bounds__(256) void scatter_kernel(
    const int* __restrict__ ei0, const int* __restrict__ ei1,
    const float* __restrict__ ew0, const float* __restrict__ ew1,
    int* __restrict__ cur01,
    int* __restrict__ srcs1, int* __restrict__ srcs2,
    float* __restrict__ ws1, float* __restrict__ ws2)
{
    int e = blockIdx.x * 256 + threadIdx.x;
    int layer = blockIdx.y;
    const int*   ei = layer ? ei1 : ei0;
    const float* ew = layer ? ew1 : ew0;
    int*   cur  = cur01 + layer * NNODES;
    int*   srcs = layer ? srcs2 : srcs1;
    float* ws   = layer ? ws2 : ws1;
    if (e < NEDGES) {
        int dst = ei[NEDGES + e];
        int pos = atomicAdd(&cur[dst], 1);
        srcs[pos] = ei[e];
        ws[pos]   = ew[e];
    }
}

// wave-per-node: xs = X @ Wn ; sq = xs.aq ; sk = xs.ak   (X is [B,N,C])
__global__ __launch_bounds__(256) void node_transform_kernel(
    const float* __restrict__ X, float* __restrict__ xs,
    const float* __restrict__ Wn, const float* __restrict__ consts,
    float* __restrict__ sq, float* __restrict__ sk)
{
    __shared__ float wnL[NC * NC];
    __shared__ float xrow[4][NB][NC + 4];
    int t = threadIdx.x, w = t >> 6, l = t & 63, b = l >> 3, o4 = l & 7;
    int n = blockIdx.x * 4 + w;
    for (int i = t; i < NC * NC; i += 256) wnL[i] = Wn[i];
    const float4* X4 = (const float4*)X;
    float4 xv = X4[((size_t)b * NNODES + n) * 8 + o4];
    ((float4*)&xrow[w][b][0])[o4] = xv;
    __syncthreads();
    float4 aq = ((const float4*)(consts + 0))[o4];
    float4 ak = ((const float4*)(consts + 32))[o4];
    const float4* wnL4 = (const float4*)wnL;
    float4 acc = {0.f, 0.f, 0.f, 0.f};
    #pragma unroll
    for (int c = 0; c < NC; ++c) {
        float xc = xrow[w][b][c];
        float4 w4 = wnL4[c * 8 + o4];
        acc.x += xc * w4.x; acc.y += xc * w4.y;
        acc.z += xc * w4.z; acc.w += xc * w4.w;
    }
    ((float4*)xs)[(size_t)n * 64 + l] = acc;
    float vq = acc.x * aq.x + acc.y * aq.y + acc.z * aq.z + acc.w * aq.w;
    float vk = acc.x * ak.x + acc.y * ak.y + acc.z * ak.z + acc.w * ak.w;
    #pragma unroll
    for (int m = 4; m >= 1; m >>= 1) {
        vq += __shfl_xor(vq, m);
        vk += __shfl_xor(vk, m);
    }
    if (o4 == 0) {
        sq[n * NB + b] = vq;
        sk[n * NB + b] = vk;
    }
}

// Persistent wave-per-node gather with work stealing. Lane = (b = l>>3, o4 = l&7), float4.
// Inline att (1 sigmoid per (edge,b), distributed by shfl), sige via LUT.
// MODE 0: fuse layer-2 node transform. MODE 1: final output [B,N,C].
template <int MODE>
__global__ __launch_bounds__(256) void gather_kernel(
    int* __restrict__ ctr,
    const int* __restrict__ rowptr, const int* __restrict__ srcs, const float* __restrict__ wsrt,
    const float* __restrict__ xs,
    const float* __restrict__ sq, const float* __restrict__ sk,
    const float* __restrict__ lut,
    const float* __restrict__ attb, const float* __restrict__ consts, int ceoff,
    const float* __restrict__ ow, const float* __restrict__ ob,
    const float* __restrict__ Wn2,
    float* __restrict__ xs2, float* __restrict__ sq2, float* __restrict__ sk2,
    float* __restrict__ outp)
{
    __shared__ __align__(16) float owL[2 * NC * NC];                 // 8 KB
    __shared__ __align__(16) float wnL[(MODE == 0) ? NC * NC : 4];   // 4 KB (MODE 0)

    int t = threadIdx.x, l = t & 63, b = l >> 3, o4 = l & 7;
    for (int i = t; i < 2 * NC * NC; i += 256) owL[i] = ow[i];
    if (MODE == 0)
        for (int i = t; i < NC * NC; i += 256) wnL[i] = Wn2[i];
    __syncthreads();   // only barrier; steal loop below is barrier-free

    const float4* owL4 = (const float4*)owL;
    const float4* wnL4 = (const float4*)wnL;
    const float4* XS4  = (const float4*)xs;
    const float4* LUT4 = (const float4*)lut;
    float ab = attb[0], ce = consts[ceoff];
    float4 ob4 = ((const float4*)ob)[o4];
    float4 aqv = {0.f,0.f,0.f,0.f}, akv = {0.f,0.f,0.f,0.f};
    if (MODE == 0) {
        aqv = ((const float4*)(consts + 64))[o4];
        akv = ((const float4*)(consts + 96))[o4];
    }

    while (true) {
        int n0 = 0;
        if (l == 0) n0 = atomicAdd(ctr, 1);
        int n = __shfl(n0, 0);
        if (n >= NNODES) break;

        int row0 = rowptr[n];
        int degp = rowptr[n + 1] - row0;    // multiple of 8
        float skb = sk[n * NB + b];
        float4 xv = XS4[(size_t)n * 64 + l];
        const int*   srcp = srcs + row0;
        const float* wp   = wsrt + row0;

        float4 acc = {0.f, 0.f, 0.f, 0.f};
        for (int c0 = 0; c0 < degp; c0 += 8) {
            // lane l owns edge (l&7)=o4 of this chunk for metadata
            int   sv = srcp[c0 + o4];
            float wv = wp[c0 + o4];
            float sqv = sq[sv * NB + b];
            float att_own = sigmoidf_(sqv + skb + wv * ce + ab);   // (edge o4, batch b)
            int idx_own = (int)(wv * (float)LUTB);
            idx_own = min(max(idx_own, 0), LUTB - 1);
            #pragma unroll
            for (int j = 0; j < 8; ++j) {
                int   s  = __shfl(sv, j);              // lane j holds edge j's src
                float at = __shfl(att_own, b * 8 + j); // (edge j, this lane's b)
                int   ix = __shfl(idx_own, j);
                float4 sg = LUT4[ix * 8 + o4];
                float4 x4 = XS4[(size_t)s * 64 + l];
                acc.x += at * sg.x * x4.x;
                acc.y += at * sg.y * x4.y;
                acc.z += at * sg.z * x4.z;
                acc.w += at * sg.w * x4.w;
            }
        }

        // wave-local epilogue: u = [xd, aggr] @ ow + ob (inputs shfl-broadcast, weights LDS)
        float4 u = ob4;
        #pragma unroll
        for (int cg = 0; cg < 8; ++cg) {
            int sl = b * 8 + cg;
            float xc0 = __shfl(xv.x, sl), xc1 = __shfl(xv.y, sl);
            float xc2 = __shfl(xv.z, sl), xc3 = __shfl(xv.w, sl);
            float ac0 = __shfl(acc.x, sl), ac1 = __shfl(acc.y, sl);
            float ac2 = __shfl(acc.z, sl), ac3 = __shfl(acc.w, sl);
            float4 w10 = owL4[(cg * 4 + 0) * 8 + o4];
            float4 w11 = owL4[(cg * 4 + 1) * 8 + o4];
            float4 w12 = owL4[(cg * 4 + 2) * 8 + o4];
            float4 w13 = owL4[(cg * 4 + 3) * 8 + o4];
            float4 w20 = owL4[(32 + cg * 4 + 0) * 8 + o4];
            float4 w21 = owL4[(32 + cg * 4 + 1) * 8 + o4];
            float4 w22 = owL4[(32 + cg * 4 + 2) * 8 + o4];
            float4 w23 = owL4[(32 + cg * 4 + 3) * 8 + o4];
            u.x += xc0*w10.x + xc1*w11.x + xc2*w12.x + xc3*w13.x
                 + ac0*w20.x + ac1*w21.x + ac2*w22.x + ac3*w23.x;
            u.y += xc0*w10.y + xc1*w11.y + xc2*w12.y + xc3*w13.y
                 + ac0*w20.y + ac1*w21.y + ac2*w22.y + ac3*w23.y;
            u.z += xc0*w10.z + xc1*w11.z + xc2*w12.z + xc3*w13.z
                 + ac0*w20.z + ac1*w21.z + ac2*w22.z + ac3*w23.z;
            u.w += xc0*w10.w + xc1*w11.w + xc2*w12.w + xc3*w13.w
                 + ac0*w20.w + ac1*w21.w + ac2*w22.w + ac3*w23.w;
        }
        float4 r;
        r.x = xv.x + u.x; r.y = xv.y + u.y; r.z = xv.z + u.z; r.w = xv.w + u.w;
        r.x = (r.x > 0.f) ? r.x : NEG_SLOPE * r.x;
        r.y = (r.y > 0.f) ? r.y : NEG_SLOPE * r.y;
        r.z = (r.z > 0.f) ? r.z : NEG_SLOPE * r.z;
        r.w = (r.w > 0.f) ? r.w : NEG_SLOPE * r.w;

        if (MODE == 1) {
            ((float4*)outp)[((size_t)b * NNODES + n) * 8 + o4] = r;
        } else {
            // fused layer-2 node transform: xs2 = h @ Wn2 ; sq2, sk2
            float4 a2 = {0.f, 0.f, 0.f, 0.f};
            #pragma unroll
            for (int cg = 0; cg < 8; ++cg) {
                int sl = b * 8 + cg;
                float h0 = __shfl(r.x, sl), h1 = __shfl(r.y, sl);
                float h2 = __shfl(r.z, sl), h3 = __shfl(r.w, sl);
                float4 w0 = wnL4[(cg * 4 + 0) * 8 + o4];
                float4 w1 = wnL4[(cg * 4 + 1) * 8 + o4];
                float4 w2 = wnL4[(cg * 4 + 2) * 8 + o4];
                float4 w3 = wnL4[(cg * 4 + 3) * 8 + o4];
                a2.x += h0*w0.x + h1*w1.x + h2*w2.x + h3*w3.x;
                a2.y += h0*w0.y + h1*w1.y + h2*w2.y + h3*w3.y;
                a2.z += h0*w0.z + h1*w1.z + h2*w2.z + h3*w3.z;
                a2.w += h0*w0.w + h1*w1.w + h2*w2.w + h3*w3.w;
            }
            ((float4*)xs2)[(size_t)n * 64 + l] = a2;
            float vq = a2.x*aqv.x + a2.y*aqv.y + a2.z*aqv.z + a2.w*aqv.w;
            float vk = a2.x*akv.x + a2.y*akv.y + a2.z*akv.z + a2.w*akv.w;
            #pragma unroll
            for (int m = 4; m >= 1; m >>= 1) {
                vq += __shfl_xor(vq, m);
                vk += __shfl_xor(vk, m);
            }
            if (o4 == 0) {
                sq2[n * NB + b] = vq;
                sk2[n * NB + b] = vk;
            }
        }
    }
}

extern "C" void kernel_launch(void* const* d_in, const int* in_sizes, int n_in,
                              void* d_out, int out_size, void* d_ws, size_t ws_size,
                              hipStream_t stream) {
    const float* X    = (const float*)d_in[0];
    const int*   ei0  = (const int*)  d_in[1];
    const int*   ei1  = (const int*)  d_in[2];
    const float* ew0  = (const float*)d_in[3];
    const float* ew1  = (const float*)d_in[4];
    const float* Wn1  = (const float*)d_in[7];
    const float* We1  = (const float*)d_in[8];
    const float* Q1   = (const float*)d_in[9];
    const float* K1   = (const float*)d_in[10];
    const float* aw1  = (const float*)d_in[11];
    const float* ab1  = (const float*)d_in[12];
    const float* ow1  = (const float*)d_in[13];
    const float* ob1  = (const float*)d_in[14];
    const float* Wn2  = (const float*)d_in[15];
    const float* We2  = (const float*)d_in[16];
    const float* Q2   = (const float*)d_in[17];
    const float* K2   = (const float*)d_in[18];
    const float* aw2  = (const float*)d_in[19];
    const float* ab2  = (const float*)d_in[20];
    const float* ow2  = (const float*)d_in[21];
    const float* ob2  = (const float*)d_in[22];

    const size_t ROW = (size_t)(NNODES + 1) * NB * NC;   // 2,560,256
    const size_t SS  = (size_t)(NNODES + 1) * NB;        // 80,008
    float* XS1    = (float*)d_ws;
    float* XS2    = XS1 + ROW;
    float* SQ1    = XS2 + ROW;
    float* SK1    = SQ1 + SS;
    float* SQ2    = SK1 + SS;
    float* SK2    = SQ2 + SS;
    float* CONSTS = SK2 + SS;                            // 160
    float* LUT    = CONSTS + 160;                        // 2*LUTB*32 (layer1 then layer2)
    int* ROWPTR1  = (int*)(LUT + 2 * LUTB * 32);
    int* ROWPTR2  = ROWPTR1 + (NNODES + 1);
    int* CNT      = ROWPTR2 + (NNODES + 1);              // 2*N
    int* NODECTR  = CNT + 2 * NNODES;                    // 32 ints (2 counters, padded)
    int* SRCS1    = NODECTR + 32;
    int* SRCS2    = SRCS1 + PADE;
    float* WS1    = (float*)(SRCS2 + PADE);
    float* WS2    = WS1 + PADE;

    const int EBLKS = (NEDGES + 255) / 256;              // 625
    const int FILLB = (PADE + 255) / 256;                // 899

    setup_kernel<<<FILLB + 1, 256, 0, stream>>>(
        Q1, K1, aw1, We1, Q2, K2, aw2, We2, CONSTS, LUT,
        SRCS1, SRCS2, WS1, WS2, CNT, NODECTR, XS1, XS2, SQ1, SK1, SQ2, SK2);
    hist_kernel<<<dim3(EBLKS, 2), 256, 0, stream>>>(ei0, ei1, CNT);
    scan_kernel<<<2, 1024, 0, stream>>>(CNT, ROWPTR1);
    scatter_kernel<<<dim3(EBLKS, 2), 256, 0, stream>>>(
        ei0, ei1, ew0, ew1, CNT, SRCS1, SRCS2, WS1, WS2);
    node_transform_kernel<<<NNODES / 4, 256, 0, stream>>>(X, XS1, Wn1, CONSTS, SQ1, SK1);

    gather_kernel<0><<<2048, 256, 0, stream>>>(
        NODECTR, ROWPTR1, SRCS1, WS1, XS1, SQ1, SK1, LUT, ab1, CONSTS, 128,
        ow1, ob1, Wn2, XS2, SQ2, SK2, nullptr);
    gather_kernel<1><<<2048, 256, 0, stream>>>(
        NODECTR + 16, ROWPTR2, SRCS2, WS2, XS2, SQ2, SK2, LUT + LUTB * 32, ab2, CONSTS, 129,
        ow2, ob2, nullptr, nullptr, nullptr, nullptr, (float*)d_out);
}

// Round 6
// 139.765 us; speedup vs baseline: 3.5804x; 3.5804x over previous
//
#include <hip/hip_runtime.h>

#define NNODES 10000
#define NEDGES 160000
#define NB 8
#define NC 32
#define PADE 230016   // >= NEDGES + 7*NNODES (buckets padded to multiple of 8)
#define LUTB 2048
constexpr float NEG_SLOPE = 0.01f;

__device__ __forceinline__ float sigmoidf_(float x) {
    return 1.0f / (1.0f + __expf(-x));
}

// ---- setup: zero counters, sentinel-fill sorted arrays, build sige LUT, fold att weights ----
// consts: [0:32) aq1, [32:64) ak1, [64:96) aq2, [96:128) ak2, [128] ce1, [129] ce2
__global__ __launch_bounds__(256) void setup_kernel(
    const float* Q1, const float* K1, const float* aw1, const float* We1,
    const float* Q2, const float* K2, const float* aw2, const float* We2,
    float* consts, float* lut,
    int* srcs1, int* srcs2, float* ws1, float* ws2,
    int* cnt,
    float* xs1, float* xs2,
    float* sq1, float* sk1, float* sq2, float* sk2)
{
    if (blockIdx.x == gridDim.x - 1) {
        int t = threadIdx.x;
        if (t < 32) {
            float aq1 = 0.f, ak1 = 0.f, aq2 = 0.f, ak2 = 0.f;
            for (int s = 0; s < 32; ++s) {
                aq1 += Q1[t * 32 + s] * aw1[s];
                ak1 += K1[t * 32 + s] * aw1[32 + s];
                aq2 += Q2[t * 32 + s] * aw2[s];
                ak2 += K2[t * 32 + s] * aw2[32 + s];
            }
            consts[t]      = aq1;
            consts[32 + t] = ak1;
            consts[64 + t] = aq2;
            consts[96 + t] = ak2;
            if (t == 0) {
                float ce1 = 0.f, ce2 = 0.f;
                for (int s = 0; s < 32; ++s) {
                    ce1 += We1[s] * aw1[64 + s];
                    ce2 += We2[s] * aw2[64 + s];
                }
                consts[128] = ce1;
                consts[129] = ce2;
            }
        }
        return;
    }
    int i = blockIdx.x * 256 + threadIdx.x;
    if (i < PADE) {
        srcs1[i] = NNODES; srcs2[i] = NNODES;
        ws1[i] = 0.f;      ws2[i] = 0.f;
    }
    if (i < 2 * LUTB * 32) {             // sige LUT, both layers
        int layer = i >> 16;             // LUTB*32 = 65536
        int bin   = (i >> 5) & (LUTB - 1);
        int o     = i & 31;
        float w   = (bin + 0.5f) * (1.0f / LUTB);
        float we  = layer ? We2[o] : We1[o];
        lut[i] = sigmoidf_(w * we);
    }
    if (i < 2 * NNODES) cnt[i] = 0;
    if (i < NB * NC) {
        xs1[(size_t)NNODES * NB * NC + i] = 0.f;
        xs2[(size_t)NNODES * NB * NC + i] = 0.f;
    }
    if (i < NB) {
        sq1[NNODES * NB + i] = 0.f; sk1[NNODES * NB + i] = 0.f;
        sq2[NNODES * NB + i] = 0.f; sk2[NNODES * NB + i] = 0.f;
    }
}

__global__ __launch_bounds__(256) void hist_kernel(
    const int* __restrict__ ei0, const int* __restrict__ ei1, int* __restrict__ cnt01)
{
    int e = blockIdx.x * 256 + threadIdx.x;
    const int* ei = blockIdx.y ? ei1 : ei0;
    int* cnt = cnt01 + blockIdx.y * NNODES;
    if (e < NEDGES) atomicAdd(&cnt[ei[NEDGES + e]], 1);
}

// block per layer: exclusive scan of counts rounded up to multiple of 8
__global__ __launch_bounds__(1024) void scan_kernel(int* cnt01, int* rowptr01)
{
    __shared__ int part[1024];
    int layer = blockIdx.x;
    int* cnt    = cnt01 + layer * NNODES;
    int* rowptr = rowptr01 + layer * (NNODES + 1);
    int t = threadIdx.x;
    int base = t * 10;
    int local[10];
    int s = 0;
    #pragma unroll
    for (int i = 0; i < 10; ++i) {
        int idx = base + i;
        int v = (idx < NNODES) ? cnt[idx] : 0;
        int vp = (v + 7) & ~7;
        local[i] = s;
        s += vp;
    }
    part[t] = s;
    __syncthreads();
    for (int off = 1; off < 1024; off <<= 1) {
        int v = (t >= off) ? part[t - off] : 0;
        __syncthreads();
        part[t] += v;
        __syncthreads();
    }
    int pre = (t == 0) ? 0 : part[t - 1];
    #pragma unroll
    for (int i = 0; i < 10; ++i) {
        int idx = base + i;
        if (idx < NNODES) {
            int p = pre + local[i];
            rowptr[idx] = p;
            cnt[idx]    = p;            // becomes scatter cursor
        }
    }
    if (t == 1023) rowptr[NNODES] = part[1023];
}

__global__ __launch_bounds__(256) void scatter_kernel(
    const int* __restrict__ ei0, const int* __restrict__ ei1,
    const float* __restrict__ ew0, const float* __restrict__ ew1,
    int* __restrict__ cur01,
    int* __restrict__ srcs1, int* __restrict__ srcs2,
    float* __restrict__ ws1, float* __restrict__ ws2)
{
    int e = blockIdx.x * 256 + threadIdx.x;
    int layer = blockIdx.y;
    const int*   ei = layer ? ei1 : ei0;
    const float* ew = layer ? ew1 : ew0;
    int*   cur  = cur01 + layer * NNODES;
    int*   srcs = layer ? srcs2 : srcs1;
    float* ws   = layer ? ws2 : ws1;
    if (e < NEDGES) {
        int dst = ei[NEDGES + e];
        int pos = atomicAdd(&cur[dst], 1);
        srcs[pos] = ei[e];
        ws[pos]   = ew[e];
    }
}

// wave-per-node: xs = X @ Wn ; sq = xs.aq ; sk = xs.ak   (X is [B,N,C])
__global__ __launch_bounds__(256) void node_transform_kernel(
    const float* __restrict__ X, float* __restrict__ xs,
    const float* __restrict__ Wn, const float* __restrict__ consts,
    float* __restrict__ sq, float* __restrict__ sk)
{
    __shared__ float wnL[NC * NC];
    __shared__ float xrow[4][NB][NC + 4];
    int t = threadIdx.x, w = t >> 6, l = t & 63, b = l >> 3, o4 = l & 7;
    int n = blockIdx.x * 4 + w;
    for (int i = t; i < NC * NC; i += 256) wnL[i] = Wn[i];
    const float4* X4 = (const float4*)X;
    float4 xv = X4[((size_t)b * NNODES + n) * 8 + o4];
    ((float4*)&xrow[w][b][0])[o4] = xv;
    __syncthreads();
    float4 aq = ((const float4*)(consts + 0))[o4];
    float4 ak = ((const float4*)(consts + 32))[o4];
    const float4* wnL4 = (const float4*)wnL;
    float4 acc = {0.f, 0.f, 0.f, 0.f};
    #pragma unroll
    for (int c = 0; c < NC; ++c) {
        float xc = xrow[w][b][c];
        float4 w4 = wnL4[c * 8 + o4];
        acc.x += xc * w4.x; acc.y += xc * w4.y;
        acc.z += xc * w4.z; acc.w += xc * w4.w;
    }
    ((float4*)xs)[(size_t)n * 64 + l] = acc;
    float vq = acc.x * aq.x + acc.y * aq.y + acc.z * aq.z + acc.w * aq.w;
    float vk = acc.x * ak.x + acc.y * ak.y + acc.z * ak.z + acc.w * ak.w;
    #pragma unroll
    for (int m = 4; m >= 1; m >>= 1) {
        vq += __shfl_xor(vq, m);
        vk += __shfl_xor(vk, m);
    }
    if (o4 == 0) {
        sq[n * NB + b] = vq;
        sk[n * NB + b] = vk;
    }
}

// Static wave-per-node gather (4 nodes/block). Lane = (b = l>>3, o4 = l&7), float4.
// Inline att (1 sigmoid per (edge,b), distributed by shfl), sige via LUT.
// Chunk metadata (src, w, sq[src]) software-pipelined one chunk ahead.
// MODE 0: fuse layer-2 node transform. MODE 1: final output [B,N,C].
template <int MODE>
__global__ __launch_bounds__(256) void gather_kernel(
    const int* __restrict__ rowptr, const int* __restrict__ srcs, const float* __restrict__ wsrt,
    const float* __restrict__ xs,
    const float* __restrict__ sq, const float* __restrict__ sk,
    const float* __restrict__ lut,
    const float* __restrict__ attb, const float* __restrict__ consts, int ceoff,
    const float* __restrict__ ow, const float* __restrict__ ob,
    const float* __restrict__ Wn2,
    float* __restrict__ xs2, float* __restrict__ sq2, float* __restrict__ sk2,
    float* __restrict__ outp)
{
    __shared__ __align__(16) float owL[2 * NC * NC];                 // 8 KB
    __shared__ __align__(16) float wnL[(MODE == 0) ? NC * NC : 4];   // 4 KB (MODE 0)

    int t = threadIdx.x, w = t >> 6, l = t & 63, b = l >> 3, o4 = l & 7;
    int n = blockIdx.x * 4 + w;
    for (int i = t; i < 2 * NC * NC; i += 256) owL[i] = ow[i];
    if (MODE == 0)
        for (int i = t; i < NC * NC; i += 256) wnL[i] = Wn2[i];
    __syncthreads();   // only barrier

    const float4* owL4 = (const float4*)owL;
    const float4* wnL4 = (const float4*)wnL;
    const float4* XS4  = (const float4*)xs;
    const float4* LUT4 = (const float4*)lut;
    float ab = attb[0], ce = consts[ceoff];
    float4 ob4 = ((const float4*)ob)[o4];

    int row0 = rowptr[n];
    int degp = rowptr[n + 1] - row0;    // multiple of 8
    float skb = sk[n * NB + b];
    float4 xv = XS4[(size_t)n * 64 + l];
    const int*   srcp = srcs + row0;
    const float* wp   = wsrt + row0;

    float4 acc = {0.f, 0.f, 0.f, 0.f};
    int sv_c = NNODES; float wv_c = 0.f, sq_c = 0.f;
    if (degp > 0) {
        sv_c = srcp[o4];                 // lane owns edge o4 of chunk
        wv_c = wp[o4];
        sq_c = sq[sv_c * NB + b];
    }
    for (int c0 = 0; c0 < degp; c0 += 8) {
        // prefetch next chunk's metadata + dependent sq gather
        int sv_n = NNODES; float wv_n = 0.f, sq_n = 0.f;
        int c1 = c0 + 8;
        if (c1 < degp) {
            sv_n = srcp[c1 + o4];
            wv_n = wp[c1 + o4];
            sq_n = sq[sv_n * NB + b];
        }
        float att_own = sigmoidf_(sq_c + skb + wv_c * ce + ab);   // (edge o4, batch b)
        int idx_own = (int)(wv_c * (float)LUTB);
        idx_own = min(max(idx_own, 0), LUTB - 1);
        #pragma unroll
        for (int j = 0; j < 8; ++j) {
            int   s  = __shfl(sv_c, j);              // lane j holds edge j's src
            float at = __shfl(att_own, b * 8 + j);   // (edge j, this lane's b)
            int   ix = __shfl(idx_own, j);
            float4 sg = LUT4[ix * 8 + o4];
            float4 x4 = XS4[(size_t)s * 64 + l];
            acc.x += at * sg.x * x4.x;
            acc.y += at * sg.y * x4.y;
            acc.z += at * sg.z * x4.z;
            acc.w += at * sg.w * x4.w;
        }
        sv_c = sv_n; wv_c = wv_n; sq_c = sq_n;
    }

    // wave-local epilogue: u = [xd, aggr] @ ow + ob (inputs shfl-broadcast, weights LDS)
    float4 u = ob4;
    #pragma unroll
    for (int cg = 0; cg < 8; ++cg) {
        int sl = b * 8 + cg;
        float xc0 = __shfl(xv.x, sl), xc1 = __shfl(xv.y, sl);
        float xc2 = __shfl(xv.z, sl), xc3 = __shfl(xv.w, sl);
        float ac0 = __shfl(acc.x, sl), ac1 = __shfl(acc.y, sl);
        float ac2 = __shfl(acc.z, sl), ac3 = __shfl(acc.w, sl);
        float4 w10 = owL4[(cg * 4 + 0) * 8 + o4];
        float4 w11 = owL4[(cg * 4 + 1) * 8 + o4];
        float4 w12 = owL4[(cg * 4 + 2) * 8 + o4];
        float4 w13 = owL4[(cg * 4 + 3) * 8 + o4];
        float4 w20 = owL4[(32 + cg * 4 + 0) * 8 + o4];
        float4 w21 = owL4[(32 + cg * 4 + 1) * 8 + o4];
        float4 w22 = owL4[(32 + cg * 4 + 2) * 8 + o4];
        float4 w23 = owL4[(32 + cg * 4 + 3) * 8 + o4];
        u.x += xc0*w10.x + xc1*w11.x + xc2*w12.x + xc3*w13.x
             + ac0*w20.x + ac1*w21.x + ac2*w22.x + ac3*w23.x;
        u.y += xc0*w10.y + xc1*w11.y + xc2*w12.y + xc3*w13.y
             + ac0*w20.y + ac1*w21.y + ac2*w22.y + ac3*w23.y;
        u.z += xc0*w10.z + xc1*w11.z + xc2*w12.z + xc3*w13.z
             + ac0*w20.z + ac1*w21.z + ac2*w22.z + ac3*w23.z;
        u.w += xc0*w10.w + xc1*w11.w + xc2*w12.w + xc3*w13.w
             + ac0*w20.w + ac1*w21.w + ac2*w22.w + ac3*w23.w;
    }
    float4 r;
    r.x = xv.x + u.x; r.y = xv.y + u.y; r.z = xv.z + u.z; r.w = xv.w + u.w;
    r.x = (r.x > 0.f) ? r.x : NEG_SLOPE * r.x;
    r.y = (r.y > 0.f) ? r.y : NEG_SLOPE * r.y;
    r.z = (r.z > 0.f) ? r.z : NEG_SLOPE * r.z;
    r.w = (r.w > 0.f) ? r.w : NEG_SLOPE * r.w;

    if (MODE == 1) {
        ((float4*)outp)[((size_t)b * NNODES + n) * 8 + o4] = r;
    } else {
        // fused layer-2 node transform: xs2 = h @ Wn2 ; sq2, sk2
        float4 aqv = ((const float4*)(consts + 64))[o4];
        float4 akv = ((const float4*)(consts + 96))[o4];
        float4 a2 = {0.f, 0.f, 0.f, 0.f};
        #pragma unroll
        for (int cg = 0; cg < 8; ++cg) {
            int sl = b * 8 + cg;
            float h0 = __shfl(r.x, sl), h1 = __shfl(r.y, sl);
            float h2 = __shfl(r.z, sl), h3 = __shfl(r.w, sl);
            float4 w0 = wnL4[(cg * 4 + 0) * 8 + o4];
            float4 w1 = wnL4[(cg * 4 + 1) * 8 + o4];
            float4 w2 = wnL4[(cg * 4 + 2) * 8 + o4];
            float4 w3 = wnL4[(cg * 4 + 3) * 8 + o4];
            a2.x += h0*w0.x + h1*w1.x + h2*w2.x + h3*w3.x;
            a2.y += h0*w0.y + h1*w1.y + h2*w2.y + h3*w3.y;
            a2.z += h0*w0.z + h1*w1.z + h2*w2.z + h3*w3.z;
            a2.w += h0*w0.w + h1*w1.w + h2*w2.w + h3*w3.w;
        }
        ((float4*)xs2)[(size_t)n * 64 + l] = a2;
        float vq = a2.x*aqv.x + a2.y*aqv.y + a2.z*aqv.z + a2.w*aqv.w;
        float vk = a2.x*akv.x + a2.y*akv.y + a2.z*akv.z + a2.w*akv.w;
        #pragma unroll
        for (int m = 4; m >= 1; m >>= 1) {
            vq += __shfl_xor(vq, m);
            vk += __shfl_xor(vk, m);
        }
        if (o4 == 0) {
            sq2[n * NB + b] = vq;
            sk2[n * NB + b] = vk;
        }
    }
}

extern "C" void kernel_launch(void* const* d_in, const int* in_sizes, int n_in,
                              void* d_out, int out_size, void* d_ws, size_t ws_size,
                              hipStream_t stream) {
    const float* X    = (const float*)d_in[0];
    const int*   ei0  = (const int*)  d_in[1];
    const int*   ei1  = (const int*)  d_in[2];
    const float* ew0  = (const float*)d_in[3];
    const float* ew1  = (const float*)d_in[4];
    const float* Wn1  = (const float*)d_in[7];
    const float* We1  = (const float*)d_in[8];
    const float* Q1   = (const float*)d_in[9];
    const float* K1   = (const float*)d_in[10];
    const float* aw1  = (const float*)d_in[11];
    const float* ab1  = (const float*)d_in[12];
    const float* ow1  = (const float*)d_in[13];
    const float* ob1  = (const float*)d_in[14];
    const float* Wn2  = (const float*)d_in[15];
    const float* We2  = (const float*)d_in[16];
    const float* Q2   = (const float*)d_in[17];
    const float* K2   = (const float*)d_in[18];
    const float* aw2  = (const float*)d_in[19];
    const float* ab2  = (const float*)d_in[20];
    const float* ow2  = (const float*)d_in[21];
    const float* ob2  = (const float*)d_in[22];

    const size_t ROW = (size_t)(NNODES + 1) * NB * NC;   // 2,560,256
    const size_t SS  = (size_t)(NNODES + 1) * NB;        // 80,008
    float* XS1    = (float*)d_ws;
    float* XS2    = XS1 + ROW;
    float* SQ1    = XS2 + ROW;
    float* SK1    = SQ1 + SS;
    float* SQ2    = SK1 + SS;
    float* SK2    = SQ2 + SS;
    float* CONSTS = SK2 + SS;                            // 160
    float* LUT    = CONSTS + 160;                        // 2*LUTB*32 (layer1 then layer2)
    int* ROWPTR1  = (int*)(LUT + 2 * LUTB * 32);
    int* ROWPTR2  = ROWPTR1 + (NNODES + 1);
    int* CNT      = ROWPTR2 + (NNODES + 1);              // 2*N
    int* SRCS1    = CNT + 2 * NNODES;
    int* SRCS2    = SRCS1 + PADE;
    float* WS1    = (float*)(SRCS2 + PADE);
    float* WS2    = WS1 + PADE;

    const int EBLKS = (NEDGES + 255) / 256;              // 625
    const int FILLB = (PADE + 255) / 256;                // 899

    setup_kernel<<<FILLB + 1, 256, 0, stream>>>(
        Q1, K1, aw1, We1, Q2, K2, aw2, We2, CONSTS, LUT,
        SRCS1, SRCS2, WS1, WS2, CNT, XS1, XS2, SQ1, SK1, SQ2, SK2);
    hist_kernel<<<dim3(EBLKS, 2), 256, 0, stream>>>(ei0, ei1, CNT);
    scan_kernel<<<2, 1024, 0, stream>>>(CNT, ROWPTR1);
    scatter_kernel<<<dim3(EBLKS, 2), 256, 0, stream>>>(
        ei0, ei1, ew0, ew1, CNT, SRCS1, SRCS2, WS1, WS2);
    node_transform_kernel<<<NNODES / 4, 256, 0, stream>>>(X, XS1, Wn1, CONSTS, SQ1, SK1);

    gather_kernel<0><<<NNODES / 4, 256, 0, stream>>>(
        ROWPTR1, SRCS1, WS1, XS1, SQ1, SK1, LUT, ab1, CONSTS, 128,
        ow1, ob1, Wn2, XS2, SQ2, SK2, nullptr);
    gather_kernel<1><<<NNODES / 4, 256, 0, stream>>>(
        ROWPTR2, SRCS2, WS2, XS2, SQ2, SK2, LUT + LUTB * 32, ab2, CONSTS, 129,
        ow2, ob2, nullptr, nullptr, nullptr, nullptr, (float*)d_out);
}

// Round 7
// 131.713 us; speedup vs baseline: 3.7993x; 1.0611x over previous
//
#include <hip/hip_runtime.h>

#define NNODES 10000
#define NEDGES 160000
#define NB 8
#define NC 32
#define PADE 230016   // >= NEDGES + 7*NNODES (buckets padded to multiple of 8)
#define LUTB 2048
#define EBLKS 625     // (NEDGES+255)/256
#define FILLB 899     // (PADE+255)/256
constexpr float NEG_SLOPE = 0.01f;

__device__ __forceinline__ float sigmoidf_(float x) {
    return 1.0f / (1.0f + __expf(-x));
}

// ---- fused: sentinel-fill sorted arrays + LUT build + consts fold + dst histogram ----
// consts: [0:32) aq1, [32:64) ak1, [64:96) aq2, [96:128) ak2, [128] ce1, [129] ce2
// cnt must be zeroed (hipMemsetAsync) before this kernel.
__global__ __launch_bounds__(256) void setup_hist_kernel(
    const float* Q1, const float* K1, const float* aw1, const float* We1,
    const float* Q2, const float* K2, const float* aw2, const float* We2,
    const int* __restrict__ ei0, const int* __restrict__ ei1,
    float* consts, float* lut,
    int* pk1, int* pk2, float* wc1, float* wc2,
    int* __restrict__ cnt,
    float* xs1, float* xs2,
    float* sq1, float* sk1, float* sq2, float* sk2)
{
    int bx = blockIdx.x;
    int t = threadIdx.x;
    if (bx < FILLB) {
        int i = bx * 256 + t;
        if (i < PADE) {
            pk1[i] = NNODES; pk2[i] = NNODES;   // sentinel: src=NNODES (zero row), ix=0
            wc1[i] = 0.f;    wc2[i] = 0.f;
        }
        if (i < 2 * LUTB * 32) {             // sige LUT, both layers
            int layer = i >> 16;             // LUTB*32 = 65536
            int bin   = (i >> 5) & (LUTB - 1);
            int o     = i & 31;
            float w   = (bin + 0.5f) * (1.0f / LUTB);
            float we  = layer ? We2[o] : We1[o];
            lut[i] = sigmoidf_(w * we);
        }
        if (i < NB * NC) {
            xs1[(size_t)NNODES * NB * NC + i] = 0.f;
            xs2[(size_t)NNODES * NB * NC + i] = 0.f;
        }
        if (i < NB) {
            sq1[NNODES * NB + i] = 0.f; sk1[NNODES * NB + i] = 0.f;
            sq2[NNODES * NB + i] = 0.f; sk2[NNODES * NB + i] = 0.f;
        }
        return;
    }
    if (bx == FILLB) {
        if (t < 32) {
            float aq1 = 0.f, ak1 = 0.f, aq2 = 0.f, ak2 = 0.f;
            for (int s = 0; s < 32; ++s) {
                aq1 += Q1[t * 32 + s] * aw1[s];
                ak1 += K1[t * 32 + s] * aw1[32 + s];
                aq2 += Q2[t * 32 + s] * aw2[s];
                ak2 += K2[t * 32 + s] * aw2[32 + s];
            }
            consts[t]      = aq1;
            consts[32 + t] = ak1;
            consts[64 + t] = aq2;
            consts[96 + t] = ak2;
            if (t == 0) {
                float ce1 = 0.f, ce2 = 0.f;
                for (int s = 0; s < 32; ++s) {
                    ce1 += We1[s] * aw1[64 + s];
                    ce2 += We2[s] * aw2[64 + s];
                }
                consts[128] = ce1;
                consts[129] = ce2;
            }
        }
        return;
    }
    int hb = bx - FILLB - 1;               // 0..2*EBLKS-1
    int layer = hb / EBLKS;
    int e = (hb % EBLKS) * 256 + t;
    const int* ei = layer ? ei1 : ei0;
    int* c = cnt + layer * NNODES;
    if (e < NEDGES) atomicAdd(&c[ei[NEDGES + e]], 1);
}

// block per layer: exclusive scan of counts rounded up to multiple of 8
__global__ __launch_bounds__(1024) void scan_kernel(int* cnt01, int* rowptr01)
{
    __shared__ int part[1024];
    int layer = blockIdx.x;
    int* cnt    = cnt01 + layer * NNODES;
    int* rowptr = rowptr01 + layer * (NNODES + 1);
    int t = threadIdx.x;
    int base = t * 10;
    int local[10];
    int s = 0;
    #pragma unroll
    for (int i = 0; i < 10; ++i) {
        int idx = base + i;
        int v = (idx < NNODES) ? cnt[idx] : 0;
        int vp = (v + 7) & ~7;
        local[i] = s;
        s += vp;
    }
    part[t] = s;
    __syncthreads();
    for (int off = 1; off < 1024; off <<= 1) {
        int v = (t >= off) ? part[t - off] : 0;
        __syncthreads();
        part[t] += v;
        __syncthreads();
    }
    int pre = (t == 0) ? 0 : part[t - 1];
    #pragma unroll
    for (int i = 0; i < 10; ++i) {
        int idx = base + i;
        if (idx < NNODES) {
            int p = pre + local[i];
            rowptr[idx] = p;
            cnt[idx]    = p;            // becomes scatter cursor
        }
    }
    if (t == 1023) rowptr[NNODES] = part[1023];
}

// ---- fused: edge scatter (with packed src|ix and wce=w*ce+ab) + node transform ----
__global__ __launch_bounds__(256) void scatter_nt_kernel(
    const int* __restrict__ ei0, const int* __restrict__ ei1,
    const float* __restrict__ ew0, const float* __restrict__ ew1,
    const float* __restrict__ ab1, const float* __restrict__ ab2,
    int* __restrict__ cur01,
    int* __restrict__ pk1, int* __restrict__ pk2,
    float* __restrict__ wc1, float* __restrict__ wc2,
    const float* __restrict__ consts,
    const float* __restrict__ X, float* __restrict__ xs,
    const float* __restrict__ Wn,
    float* __restrict__ sq, float* __restrict__ sk)
{
    __shared__ float wnL[NC * NC];
    __shared__ float xrow[4][NB][NC + 4];
    int bx = blockIdx.x;
    int t = threadIdx.x;

    if (bx < 2 * EBLKS) {
        int layer = bx / EBLKS;
        int e = (bx % EBLKS) * 256 + t;
        if (e < NEDGES) {
            const int*   ei = layer ? ei1 : ei0;
            const float* ew = layer ? ew1 : ew0;
            float ce = consts[128 + layer];
            float ab = layer ? ab2[0] : ab1[0];
            int dst = ei[NEDGES + e];
            float w = ew[e];
            int pos = atomicAdd(&cur01[layer * NNODES + dst], 1);
            int ix = (int)(w * (float)LUTB);
            ix = min(max(ix, 0), LUTB - 1);
            (layer ? pk2 : pk1)[pos] = ei[e] | (ix << 14);
            (layer ? wc2 : wc1)[pos] = w * ce + ab;
        }
        return;
    }

    // node transform: xs = X @ Wn ; sq = xs.aq ; sk = xs.ak   (X is [B,N,C])
    int w = t >> 6, l = t & 63, b = l >> 3, o4 = l & 7;
    int n = (bx - 2 * EBLKS) * 4 + w;
    for (int i = t; i < NC * NC; i += 256) wnL[i] = Wn[i];
    const float4* X4 = (const float4*)X;
    float4 xv = X4[((size_t)b * NNODES + n) * 8 + o4];
    ((float4*)&xrow[w][b][0])[o4] = xv;
    __syncthreads();
    float4 aq = ((const float4*)(consts + 0))[o4];
    float4 ak = ((const float4*)(consts + 32))[o4];
    const float4* wnL4 = (const float4*)wnL;
    float4 acc = {0.f, 0.f, 0.f, 0.f};
    #pragma unroll
    for (int c = 0; c < NC; ++c) {
        float xc = xrow[w][b][c];
        float4 w4 = wnL4[c * 8 + o4];
        acc.x += xc * w4.x; acc.y += xc * w4.y;
        acc.z += xc * w4.z; acc.w += xc * w4.w;
    }
    ((float4*)xs)[(size_t)n * 64 + l] = acc;
    float vq = acc.x * aq.x + acc.y * aq.y + acc.z * aq.z + acc.w * aq.w;
    float vk = acc.x * ak.x + acc.y * ak.y + acc.z * ak.z + acc.w * ak.w;
    #pragma unroll
    for (int m = 4; m >= 1; m >>= 1) {
        vq += __shfl_xor(vq, m);
        vk += __shfl_xor(vk, m);
    }
    if (o4 == 0) {
        sq[n * NB + b] = vq;
        sk[n * NB + b] = vk;
    }
}

// Static wave-per-node gather (4 nodes/block). Lane = (b = l>>3, o4 = l&7), float4.
// Per 8-edge chunk: 1 broadcast metadata load; per edge j: readlane -> SGPR src/ix
// (scalar-addressed xs/LUT loads, no bpermute on the address path), 1 shfl for att.
// MODE 0: fuse layer-2 node transform. MODE 1: final output [B,N,C].
template <int MODE>
__global__ __launch_bounds__(256) void gather_kernel(
    const int* __restrict__ rowptr, const int* __restrict__ pks, const float* __restrict__ wcs,
    const float* __restrict__ xs,
    const float* __restrict__ sq, const float* __restrict__ sk,
    const float* __restrict__ lut,
    const float* __restrict__ consts,
    const float* __restrict__ ow, const float* __restrict__ ob,
    const float* __restrict__ Wn2,
    float* __restrict__ xs2, float* __restrict__ sq2, float* __restrict__ sk2,
    float* __restrict__ outp)
{
    __shared__ __align__(16) float owL[2 * NC * NC];                 // 8 KB
    __shared__ __align__(16) float wnL[(MODE == 0) ? NC * NC : 4];   // 4 KB (MODE 0)

    int t = threadIdx.x, w = t >> 6, l = t & 63, b = l >> 3, o4 = l & 7;
    int n = blockIdx.x * 4 + w;
    for (int i = t; i < 2 * NC * NC; i += 256) owL[i] = ow[i];
    if (MODE == 0)
        for (int i = t; i < NC * NC; i += 256) wnL[i] = Wn2[i];
    __syncthreads();   // only barrier

    const float4* owL4 = (const float4*)owL;
    const float4* wnL4 = (const float4*)wnL;
    const float4* XS4  = (const float4*)xs;
    const float4* LUT4 = (const float4*)lut;
    float4 ob4 = ((const float4*)ob)[o4];

    int row0 = rowptr[n];
    int degp = rowptr[n + 1] - row0;    // multiple of 8
    float skb = sk[n * NB + b];
    float4 xv = XS4[(size_t)n * 64 + l];
    const int*   pkp = pks + row0;
    const float* wcp = wcs + row0;

    float4 acc = {0.f, 0.f, 0.f, 0.f};
    int pkv = NNODES; float wcv = 0.f, sqv = 0.f;
    if (degp > 0) {
        pkv = pkp[o4];                  // lane owns edge o4 of chunk (broadcast x8)
        wcv = wcp[o4];
        sqv = sq[(pkv & 16383) * NB + b];
    }
    for (int c0 = 0; c0 < degp; c0 += 8) {
        // prefetch next chunk's metadata + dependent sq gather
        int pkv_n = NNODES; float wcv_n = 0.f, sqv_n = 0.f;
        int c1 = c0 + 8;
        if (c1 < degp) {
            pkv_n = pkp[c1 + o4];
            wcv_n = wcp[c1 + o4];
            sqv_n = sq[(pkv_n & 16383) * NB + b];
        }
        float att_own = sigmoidf_(sqv + skb + wcv);   // (edge o4, batch b)
        #pragma unroll
        for (int j = 0; j < 8; ++j) {
            int spk  = __builtin_amdgcn_readlane(pkv, j);   // SGPR: edge j metadata
            int ssrc = spk & 16383;
            int six  = (spk >> 14) & 2047;
            float4 x4 = XS4[(size_t)ssrc * 64 + l];          // scalar-base + lane offset
            float4 sg = LUT4[six * 8 + o4];                  // scalar-base + lane offset
            float at = __shfl(att_own, b * 8 + j);           // (edge j, this lane's b)
            acc.x += at * sg.x * x4.x;
            acc.y += at * sg.y * x4.y;
            acc.z += at * sg.z * x4.z;
            acc.w += at * sg.w * x4.w;
        }
        pkv = pkv_n; wcv = wcv_n; sqv = sqv_n;
    }

    // wave-local epilogue: u = [xd, aggr] @ ow + ob (inputs shfl-broadcast, weights LDS)
    float4 u = ob4;
    #pragma unroll
    for (int cg = 0; cg < 8; ++cg) {
        int sl = b * 8 + cg;
        float xc0 = __shfl(xv.x, sl), xc1 = __shfl(xv.y, sl);
        float xc2 = __shfl(xv.z, sl), xc3 = __shfl(xv.w, sl);
        float ac0 = __shfl(acc.x, sl), ac1 = __shfl(acc.y, sl);
        float ac2 = __shfl(acc.z, sl), ac3 = __shfl(acc.w, sl);
        float4 w10 = owL4[(cg * 4 + 0) * 8 + o4];
        float4 w11 = owL4[(cg * 4 + 1) * 8 + o4];
        float4 w12 = owL4[(cg * 4 + 2) * 8 + o4];
        float4 w13 = owL4[(cg * 4 + 3) * 8 + o4];
        float4 w20 = owL4[(32 + cg * 4 + 0) * 8 + o4];
        float4 w21 = owL4[(32 + cg * 4 + 1) * 8 + o4];
        float4 w22 = owL4[(32 + cg * 4 + 2) * 8 + o4];
        float4 w23 = owL4[(32 + cg * 4 + 3) * 8 + o4];
        u.x += xc0*w10.x + xc1*w11.x + xc2*w12.x + xc3*w13.x
             + ac0*w20.x + ac1*w21.x + ac2*w22.x + ac3*w23.x;
        u.y += xc0*w10.y + xc1*w11.y + xc2*w12.y + xc3*w13.y
             + ac0*w20.y + ac1*w21.y + ac2*w22.y + ac3*w23.y;
        u.z += xc0*w10.z + xc1*w11.z + xc2*w12.z + xc3*w13.z
             + ac0*w20.z + ac1*w21.z + ac2*w22.z + ac3*w23.z;
        u.w += xc0*w10.w + xc1*w11.w + xc2*w12.w + xc3*w13.w
             + ac0*w20.w + ac1*w21.w + ac2*w22.w + ac3*w23.w;
    }
    float4 r;
    r.x = xv.x + u.x; r.y = xv.y + u.y; r.z = xv.z + u.z; r.w = xv.w + u.w;
    r.x = (r.x > 0.f) ? r.x : NEG_SLOPE * r.x;
    r.y = (r.y > 0.f) ? r.y : NEG_SLOPE * r.y;
    r.z = (r.z > 0.f) ? r.z : NEG_SLOPE * r.z;
    r.w = (r.w > 0.f) ? r.w : NEG_SLOPE * r.w;

    if (MODE == 1) {
        ((float4*)outp)[((size_t)b * NNODES + n) * 8 + o4] = r;
    } else {
        // fused layer-2 node transform: xs2 = h @ Wn2 ; sq2, sk2
        float4 aqv = ((const float4*)(consts + 64))[o4];
        float4 akv = ((const float4*)(consts + 96))[o4];
        float4 a2 = {0.f, 0.f, 0.f, 0.f};
        #pragma unroll
        for (int cg = 0; cg < 8; ++cg) {
            int sl = b * 8 + cg;
            float h0 = __shfl(r.x, sl), h1 = __shfl(r.y, sl);
            float h2 = __shfl(r.z, sl), h3 = __shfl(r.w, sl);
            float4 w0 = wnL4[(cg * 4 + 0) * 8 + o4];
            float4 w1 = wnL4[(cg * 4 + 1) * 8 + o4];
            float4 w2 = wnL4[(cg * 4 + 2) * 8 + o4];
            float4 w3 = wnL4[(cg * 4 + 3) * 8 + o4];
            a2.x += h0*w0.x + h1*w1.x + h2*w2.x + h3*w3.x;
            a2.y += h0*w0.y + h1*w1.y + h2*w2.y + h3*w3.y;
            a2.z += h0*w0.z + h1*w1.z + h2*w2.z + h3*w3.z;
            a2.w += h0*w0.w + h1*w1.w + h2*w2.w + h3*w3.w;
        }
        ((float4*)xs2)[(size_t)n * 64 + l] = a2;
        float vq = a2.x*aqv.x + a2.y*aqv.y + a2.z*aqv.z + a2.w*aqv.w;
        float vk = a2.x*akv.x + a2.y*akv.y + a2.z*akv.z + a2.w*akv.w;
        #pragma unroll
        for (int m = 4; m >= 1; m >>= 1) {
            vq += __shfl_xor(vq, m);
            vk += __shfl_xor(vk, m);
        }
        if (o4 == 0) {
            sq2[n * NB + b] = vq;
            sk2[n * NB + b] = vk;
        }
    }
}

extern "C" void kernel_launch(void* const* d_in, const int* in_sizes, int n_in,
                              void* d_out, int out_size, void* d_ws, size_t ws_size,
                              hipStream_t stream) {
    const float* X    = (const float*)d_in[0];
    const int*   ei0  = (const int*)  d_in[1];
    const int*   ei1  = (const int*)  d_in[2];
    const float* ew0  = (const float*)d_in[3];
    const float* ew1  = (const float*)d_in[4];
    const float* Wn1  = (const float*)d_in[7];
    const float* We1  = (const float*)d_in[8];
    const float* Q1   = (const float*)d_in[9];
    const float* K1   = (const float*)d_in[10];
    const float* aw1  = (const float*)d_in[11];
    const float* ab1  = (const float*)d_in[12];
    const float* ow1  = (const float*)d_in[13];
    const float* ob1  = (const float*)d_in[14];
    const float* Wn2  = (const float*)d_in[15];
    const float* We2  = (const float*)d_in[16];
    const float* Q2   = (const float*)d_in[17];
    const float* K2   = (const float*)d_in[18];
    const float* aw2  = (const float*)d_in[19];
    const float* ab2  = (const float*)d_in[20];
    const float* ow2  = (const float*)d_in[21];
    const float* ob2  = (const float*)d_in[22];

    const size_t ROW = (size_t)(NNODES + 1) * NB * NC;   // 2,560,256
    const size_t SS  = (size_t)(NNODES + 1) * NB;        // 80,008
    float* XS1    = (float*)d_ws;
    float* XS2    = XS1 + ROW;
    float* SQ1    = XS2 + ROW;
    float* SK1    = SQ1 + SS;
    float* SQ2    = SK1 + SS;
    float* SK2    = SQ2 + SS;
    float* CONSTS = SK2 + SS;                            // 160
    float* LUT    = CONSTS + 160;                        // 2*LUTB*32 (layer1 then layer2)
    int* ROWPTR1  = (int*)(LUT + 2 * LUTB * 32);
    int* ROWPTR2  = ROWPTR1 + (NNODES + 1);
    int* CNT      = ROWPTR2 + (NNODES + 1);              // 2*N (hist -> cursor)
    int* PK1      = CNT + 2 * NNODES;
    int* PK2      = PK1 + PADE;
    float* WC1    = (float*)(PK2 + PADE);
    float* WC2    = WC1 + PADE;

    hipMemsetAsync(CNT, 0, 2 * NNODES * sizeof(int), stream);
    setup_hist_kernel<<<FILLB + 1 + 2 * EBLKS, 256, 0, stream>>>(
        Q1, K1, aw1, We1, Q2, K2, aw2, We2, ei0, ei1,
        CONSTS, LUT, PK1, PK2, WC1, WC2, CNT, XS1, XS2, SQ1, SK1, SQ2, SK2);
    scan_kernel<<<2, 1024, 0, stream>>>(CNT, ROWPTR1);
    scatter_nt_kernel<<<2 * EBLKS + NNODES / 4, 256, 0, stream>>>(
        ei0, ei1, ew0, ew1, ab1, ab2, CNT, PK1, PK2, WC1, WC2, CONSTS,
        X, XS1, Wn1, SQ1, SK1);

    gather_kernel<0><<<NNODES / 4, 256, 0, stream>>>(
        ROWPTR1, PK1, WC1, XS1, SQ1, SK1, LUT, CONSTS,
        ow1, ob1, Wn2, XS2, SQ2, SK2, nullptr);
    gather_kernel<1><<<NNODES / 4, 256, 0, stream>>>(
        ROWPTR2, PK2, WC2, XS2, SQ2, SK2, LUT + LUTB * 32, CONSTS,
        ow2, ob2, nullptr, nullptr, nullptr, nullptr, (float*)d_out);
}